// Round 10
// baseline (624.173 us; speedup 1.0000x reference)
//
#include <hip/hip_runtime.h>
#include <math.h>

// AugmentPipe: flip -> affine(rot/scale/trans) bilinear-reflect sample ->
// brightness -> contrast -> saturation -> cutout(noise). One fused pass.
// B=64, C=3, H=W=512, float32 in/out.
//
// R11 -> R12. Six structures pinned at 182-190us. Cross-round elimination:
// HBM reads varied 1.9x (R8 266MB vs R9 140MB) at equal time; VALU 28-52%,
// conflicts 0-7M, NT-vs-cached, full-vs-half-line stores all varied with no
// effect. Remaining shared element: intra-block synchronization (2 barriers
// per tile convoy 4 waves; ~6 independent blocks/CU are the only latency
// hiders). R12 removes ALL synchronization:
//   (1) WAVE-PRIVATE staging: each wave owns an 8x8 output tile + a private
//       3.75KB LDS slice. Box is compile-time 20x16 (8px affine span
//       7*1.2045*sqrt2 ~ 11.9 + taps + slack + 4-align <= 20 wide, <= 16
//       tall) -- always fully staged, no fh, no participation mask.
//   (2) ZERO barriers. Staging->gather ordering is intra-wave program order
//       (DS queue in-order per wave; compiler's lgkmcnt covers it).
//   (3) Each wave strides 16 tiles across a 512x8 band (setup amortized),
//       self-pipelined: loads(t+1) issued between ds_write(t) and gather(t)
//       -- gather+compute hides the HBM latency, no cross-wave coupling.
//   (4) launch_bounds(256,8): LDS 15.36KB/block, VGPR<=64 -> 32 independent
//       waves/CU (vs ~6 independent units in all prior variants).
// Kept: virtual-reflect staging (R10-exact: R(v)=v<0?-1-v:(v>511?1023-v:v)
// on taps == reference reflect-floor-clamp), XCD swizzle, incremental
// affine, fmed3 clamps, cached stores (R11), 32-bit saddr offsets.

constexpr int Bn = 64;
constexpr int Cn = 3;
constexpr int Hn = 512;
constexpr int Wn = 512;
constexpr float TRANSLATE_STD = 0.125f;
constexpr float SCALE_STD = 0.2f;
constexpr int CUT_H = 256; // int(512*0.5)
constexpr int CUT_W = 256;

constexpr int FW = 20;        // wave box width (16 quad + 4 extra cols)
constexpr int FH = 16;        // wave box height (always fully staged)
constexpr int FSTR = 20;      // LDS row stride, 80B (16B-aligned rows)
constexpr int SLICE = FSTR * FH;      // 320 floats per channel
constexpr int WSLICE = Cn * SLICE;    // 960 floats per wave slice
constexpr int NT = 16;        // tiles per wave (x stride 32)
constexpr uint32_t PLANE = 512u * 512u;

typedef float f4v __attribute__((ext_vector_type(4)));

// Integer reflect of a virtual tap index into [0,511]; valid v in
// [-512,1022], our range is [-211,722]. Reflect of a 4-aligned quad stays
// 4-aligned (asc or desc), so dwordx4 source loads stay 16B-aligned.
__device__ __forceinline__ int refl(int v) {
    v = (v < 0) ? (-1 - v) : v;
    return (v > 511) ? (1023 - v) : v;
}

__global__ __launch_bounds__(256, 8) void augment_kernel(
    const float* __restrict__ images,
    const float* __restrict__ u_angle,
    const float* __restrict__ u_scale,
    const float* __restrict__ u_trans,
    const float* __restrict__ u_bright,
    const float* __restrict__ u_contrast,
    const float* __restrict__ u_sat,
    const float* __restrict__ noise,
    const int* __restrict__ m_flip,
    const int* __restrict__ m_rot,
    const int* __restrict__ m_scale,
    const int* __restrict__ m_trans,
    const int* __restrict__ m_bright,
    const int* __restrict__ m_contrast,
    const int* __restrict__ m_sat,
    const int* __restrict__ m_cut,
    const int* __restrict__ y0p,
    const int* __restrict__ x0p,
    float* __restrict__ out)
{
    __shared__ __align__(16) float lds[4 * WSLICE];   // 15360 B -> 8 blk/CU

    const int tid  = threadIdx.x;
    const int wid  = tid >> 6;            // wave 0..3 (private LDS slice)
    const int lane = tid & 63;
    const int lx   = lane & 7;            // pixel col within 8x8 tile
    const int ly   = lane >> 3;           // pixel row within 8x8 tile
    const int srow = lane >> 2;           // staging row 0..15
    const int sq   = (lane & 3) << 2;     // staging quad col 0,4,8,12
    const int sqe  = 16 + (lane & 3);     // staging extra col 16..19

    // XCD swizzle: 4096 blocks; each XCD (lin%8) gets 512 contiguous =
    // 8 whole batches (L2-resident), band-major inside.
    const int lin  = blockIdx.x + (blockIdx.y << 6);
    const int loc  = lin >> 3;
    const int b    = ((lin & 7) << 3) + (loc >> 6);   // batch
    const int band = loc & 63;                         // 8-row band

    const int y = (band << 3) + ly;

    // ---- Per-batch setup (amortized over 16 tiles).
    const float angle = (m_rot[b] > 0) ? (u_angle[b] * 2.0f - 1.0f) * 3.14159265358979323846f : 0.0f;
    const float sc    = (m_scale[b] > 0) ? (u_scale[b] * 2.0f - 1.0f) * SCALE_STD + 1.0f : 1.0f;
    const float tr    = (m_trans[b] > 0) ? (u_trans[b] * 2.0f - 1.0f) * TRANSLATE_STD : 0.0f;
    const float bb    = (m_bright[b] > 0) ? u_bright[b] * 0.2f : 0.0f;
    const float cc    = (m_contrast[b] > 0) ? u_contrast[b] + 0.5f : 1.0f;
    const float ss    = (m_sat[b] > 0) ? u_sat[b] * 2.0f : 1.0f;
    const bool  flip  = m_flip[b] > 0;
    const bool  docut = m_cut[b] > 0;
    const int   cy0   = y0p[b];
    const int   cx0   = x0p[b];

    float saf, caf;
    __sincosf(angle, &saf, &caf);

    // Incremental affine basis (validated R6..R11).
    const float kk = sc * (512.0f / 511.0f);
    const float dxdx = caf * kk, dxdy = -saf * kk;
    const float dydx = saf * kk, dydy = caf * kk;
    const float xx_org = 256.0f * (sc * (saf - caf) + tr + 1.0f) - 0.5f;
    const float yy_org = 256.0f * (sc * (-saf - caf) + tr + 1.0f) - 0.5f;

    const float step_x = 32.0f * dxdx;    // wave x-stride per tile
    const float step_y = 32.0f * dydx;

    const float w8 = (float)(wid << 3);
    const float b8 = (float)(band << 3);

    float xxt = xx_org + (w8 + (float)lx) * dxdx + (float)y * dxdy;
    float yyt = yy_org + (w8 + (float)lx) * dydx + (float)y * dydy;

    float bx = xx_org + w8 * dxdx + b8 * dxdy;   // rolling wave-tile corner
    float by = yy_org + w8 * dydx + b8 * dydy;
    const float sxx = 7.0f * dxdx, sxy = 7.0f * dxdy;
    const float syx = 7.0f * dydx, syy = 7.0f * dydy;
    const float min_dx = fminf(sxx, 0.0f) + fminf(sxy, 0.0f);
    const float min_dy = fminf(syx, 0.0f) + fminf(syy, 0.0f);

    const float* __restrict__ imgb = images + (size_t)b * (Cn * PLANE);
    float* __restrict__ outb       = out    + (size_t)b * (Cn * PLANE);
    const float* __restrict__ noib = noise  + (size_t)b * (Cn * PLANE);

    float* const wbase = lds + wid * WSLICE;     // private slice

    const bool ycut = docut && (y >= cy0) && (y < cy0 + CUT_H);
    uint32_t opix = (uint32_t)y * 512u + (uint32_t)((wid << 3) + lx);

    // Box: top-left only (box size is compile-time FWxFH; bounds proven:
    // span<=11.95 -> cols needed <=16+3align<=19, rows needed <=14<=16).
    int x_lo, y_lo, nx_lo, ny_lo;
    auto mkbox = [&](float bxv, float byv, int& xl, int& yl) {
        xl = (((int)floorf(bxv + min_dx)) - 1) & ~3;   // rounds toward -inf
        yl = ((int)floorf(byv + min_dy)) - 1;
    };

    // Prefetch registers: one quad + one extra dword per channel.
    f4v A{}, Bq{}, Cq{};
    float Ae = 0.f, Be = 0.f, Ce = 0.f;
    bool rev = false;

    auto loadR = [&](int xl, int yl) {
        const uint32_t ro = (uint32_t)refl(yl + srow) * 512u;
        const int c0 = xl + sq;
        int S0 = refl(c0);     if (flip) S0 = 511 - S0;
        int S3 = refl(c0 + 3); if (flip) S3 = 511 - S3;
        const int d = S3 - S0;
        if (d == 3) {                     // contiguous ascending
            rev = false;
            __builtin_memcpy(&A,  imgb + ro + S0, 16);
            __builtin_memcpy(&Bq, imgb + ro + S0 + PLANE, 16);
            __builtin_memcpy(&Cq, imgb + ro + S0 + 2 * PLANE, 16);
        } else if (d == -3) {             // contiguous descending
            rev = true;
            __builtin_memcpy(&A,  imgb + ro + S3, 16);
            __builtin_memcpy(&Bq, imgb + ro + S3 + PLANE, 16);
            __builtin_memcpy(&Cq, imgb + ro + S3 + 2 * PLANE, 16);
        } else {                          // fold inside quad (rare lanes)
            rev = false;
            int S1 = refl(c0 + 1); if (flip) S1 = 511 - S1;
            int S2 = refl(c0 + 2); if (flip) S2 = 511 - S2;
            A  = f4v{imgb[ro + S0], imgb[ro + S1], imgb[ro + S2], imgb[ro + S3]};
            const float* p1 = imgb + PLANE;
            Bq = f4v{p1[ro + S0], p1[ro + S1], p1[ro + S2], p1[ro + S3]};
            const float* p2 = imgb + 2 * PLANE;
            Cq = f4v{p2[ro + S0], p2[ro + S1], p2[ro + S2], p2[ro + S3]};
        }
        int Se = refl(xl + sqe); if (flip) Se = 511 - Se;
        Ae = imgb[ro + Se];
        Be = imgb[ro + Se + PLANE];
        Ce = imgb[ro + Se + 2 * PLANE];
    };

    auto writeR = [&]() {
        f4v a = A, b2 = Bq, c2 = Cq;
        if (rev) {
            a  = f4v{A.w,  A.z,  A.y,  A.x};
            b2 = f4v{Bq.w, Bq.z, Bq.y, Bq.x};
            c2 = f4v{Cq.w, Cq.z, Cq.y, Cq.x};
        }
        float* d0 = wbase + srow * FSTR + sq;
        *(f4v*)(d0)             = a;
        *(f4v*)(d0 + SLICE)     = b2;
        *(f4v*)(d0 + 2 * SLICE) = c2;
        float* de = wbase + srow * FSTR + sqe;
        de[0]         = Ae;
        de[SLICE]     = Be;
        de[2 * SLICE] = Ce;
    };

    // ---- Prologue: tile0 loads in flight.
    mkbox(bx, by, x_lo, y_lo);
    loadR(x_lo, y_lo);

    #pragma unroll 1
    for (int t = 0; t < NT; ++t) {
        writeR();                          // counted vmcnt on this tile's loads
        const int cxl = x_lo, cyl = y_lo;
        if (t + 1 < NT) {                  // issue next tile's loads now --
            bx += step_x; by += step_y;    // they fly under gather+compute
            mkbox(bx, by, nx_lo, ny_lo);
            loadR(nx_lo, ny_lo);
            x_lo = nx_lo; y_lo = ny_lo;
        }

        // ---- Exact bilinear from the private slice (lgkmcnt auto; DS ops
        // of one wave execute in order, so no barrier is needed).
        const float fx = xxt - (float)cxl;
        const float fy = yyt - (float)cyl;
        const int xi = (int)fx;
        const int yi = (int)fy;
        const float wx = fx - (float)xi;
        const float wy = fy - (float)yi;
        const float* p = wbase + yi * FSTR + xi;

        float vals[Cn];
        #pragma unroll
        for (int c = 0; c < Cn; ++c) {
            const float v00 = p[0], v01 = p[1];
            const float v10 = p[FSTR], v11 = p[FSTR + 1];
            p += SLICE;
            const float top = v00 + wx * (v01 - v00);
            const float bot = v10 + wx * (v11 - v10);
            float v = top + wy * (bot - top);
            v = __builtin_amdgcn_fmed3f(v + bb, -1.0f, 1.0f);  // brightness
            v = __builtin_amdgcn_fmed3f(v * cc, -1.0f, 1.0f);  // contrast
            vals[c] = v;
        }

        // ---- Saturation + cutout + store (cached; R11).
        const float gray = (vals[0] + vals[1] + vals[2]) * (1.0f / 3.0f);
        const int xpix = (wid << 3) + (t << 5) + lx;
        const bool cut = ycut && (xpix >= cx0) && (xpix < cx0 + CUT_W);
        #pragma unroll
        for (int c = 0; c < Cn; ++c) {
            float v = gray + ss * (vals[c] - gray);
            v = __builtin_amdgcn_fmed3f(v, -1.0f, 1.0f);
            if (cut) v = noib[opix + c * PLANE];
            outb[opix + c * PLANE] = v;
        }
        opix += 32;
        xxt += step_x; yyt += step_y;
    }
}

extern "C" void kernel_launch(void* const* d_in, const int* in_sizes, int n_in,
                              void* d_out, int out_size, void* d_ws, size_t ws_size,
                              hipStream_t stream) {
    const float* images     = (const float*)d_in[0];
    const float* u_angle    = (const float*)d_in[1];
    const float* u_scale    = (const float*)d_in[2];
    const float* u_trans    = (const float*)d_in[3];
    const float* u_bright   = (const float*)d_in[4];
    const float* u_contrast = (const float*)d_in[5];
    const float* u_sat      = (const float*)d_in[6];
    const float* noise      = (const float*)d_in[7];
    const int*   m_flip     = (const int*)d_in[8];
    const int*   m_rot      = (const int*)d_in[9];
    const int*   m_scale    = (const int*)d_in[10];
    const int*   m_trans    = (const int*)d_in[11];
    const int*   m_bright   = (const int*)d_in[12];
    const int*   m_contrast = (const int*)d_in[13];
    const int*   m_sat      = (const int*)d_in[14];
    const int*   m_cut      = (const int*)d_in[15];
    const int*   y0p        = (const int*)d_in[16];
    const int*   x0p        = (const int*)d_in[17];
    float* out = (float*)d_out;

    dim3 block(256, 1, 1);
    dim3 grid(64, 64, 1);   // 4096 blocks: (band, batch) via swizzle
    augment_kernel<<<grid, block, 0, stream>>>(
        images, u_angle, u_scale, u_trans, u_bright, u_contrast, u_sat, noise,
        m_flip, m_rot, m_scale, m_trans, m_bright, m_contrast, m_sat, m_cut,
        y0p, x0p, out);
}

// Round 11
// 527.415 us; speedup vs baseline: 1.1835x; 1.1835x over previous
//
#include <hip/hip_runtime.h>
#include <math.h>

// AugmentPipe: flip -> affine(rot/scale/trans) bilinear-reflect sample ->
// brightness -> contrast -> saturation -> cutout(noise). One fused pass.
// B=64, C=3, H=W=512, float32 in/out.
//
// R12 -> R14. R12 (zero-barrier wave-private) regressed 188->303: falsifies
// the sync theory (R5 no-prefetch and R9 prefetched both 183; removing
// barriers hurt). Time tracks total per-px instruction work. Fresh look:
// the workload is a MIXTURE. Only rotated batches (half: m_rot=1) have
// diagonal footprints; axis-aligned batches (angle exactly 0 -> saf==0.0f
// exactly) have per-row-uniform y-taps and lane-consecutive x-taps, so the
// R2-style direct gather touches only ~5-6 lines/instr -- already cheap.
// Since R5, axis blocks have paid the full staging tax (3 loads + 3
// ds_writes + 12 ds_reads + 2 barriers per px-group) for a problem they
// don't have. R14 = class dispatch per block (batch-uniform branch):
//   rotated -> R11 staged virtual-reflect pipeline (verbatim, proven);
//   axis    -> direct per-px gather (R9 fallback code verbatim, proven):
//              no LDS, no barriers.
// A/B readout: conflicts should halve (axis blocks do zero LDS); if time is
// flat, the rotated half is dominant and path-invariant.
// Kept: XCD swizzle, NT=8 strip, incremental affine, reg-prefetch,
// lgkmcnt-only pipe_barrier, FSTRIDE 40, fmed3, cached stores, 32-bit saddr.

constexpr int Bn = 64;
constexpr int Cn = 3;
constexpr int Hn = 512;
constexpr int Wn = 512;
constexpr float TRANSLATE_STD = 0.125f;
constexpr float SCALE_STD = 0.2f;
constexpr int CUT_H = 256; // int(512*0.5)
constexpr int CUT_W = 256;

constexpr int FW = 32;        // staged virtual box width (8 threads x 4 cols)
constexpr int FSTRIDE = 40;   // LDS row stride (160B, 16B-aligned rows)
constexpr int FH_MAX = 32;    // staged rows capacity (math bound 30)
constexpr int CH_LDS = FSTRIDE * FH_MAX;   // 1280 floats per channel
constexpr int NT = 8;         // tiles per block (128x16 strip)
constexpr uint32_t PLANE = 512u * 512u;

typedef float f4v __attribute__((ext_vector_type(4)));
typedef float f2v __attribute__((ext_vector_type(2)));

__device__ __forceinline__ f2v load2(const float* p) {
    f2v r;
    __builtin_memcpy(&r, p, 8);
    return r;
}

// Integer reflect of a virtual tap index into [0,511]; valid v in
// [-512,1022], our range is [-211,722].
__device__ __forceinline__ int refl(int v) {
    v = (v < 0) ? (-1 - v) : v;
    return (v > 511) ? (1023 - v) : v;
}

// Float reflect (reference semantics) for the axis gather path.
__device__ __forceinline__ float reflect_coord(float v, float size) {
    v = fabsf(v + 0.5f);
    v = fmodf(v, 2.0f * size);
    v = fminf(v, 2.0f * size - v);
    return fminf(fmaxf(v - 0.5f, 0.0f), size - 1.0f);
}

// Barrier that drains DS ops only; VMEM stays in flight across it.
__device__ __forceinline__ void pipe_barrier() {
    asm volatile("s_waitcnt lgkmcnt(0)" ::: "memory");
    __builtin_amdgcn_s_barrier();
    __builtin_amdgcn_sched_barrier(0);
}

__global__ __launch_bounds__(256) void augment_kernel(
    const float* __restrict__ images,
    const float* __restrict__ u_angle,
    const float* __restrict__ u_scale,
    const float* __restrict__ u_trans,
    const float* __restrict__ u_bright,
    const float* __restrict__ u_contrast,
    const float* __restrict__ u_sat,
    const float* __restrict__ noise,
    const int* __restrict__ m_flip,
    const int* __restrict__ m_rot,
    const int* __restrict__ m_scale,
    const int* __restrict__ m_trans,
    const int* __restrict__ m_bright,
    const int* __restrict__ m_contrast,
    const int* __restrict__ m_sat,
    const int* __restrict__ m_cut,
    const int* __restrict__ y0p,
    const int* __restrict__ x0p,
    float* __restrict__ out)
{
    __shared__ __align__(16) float lds[Cn * CH_LDS];   // 15360 B -> 8 blk/CU

    // XCD swizzle: each XCD (lin%8) gets a contiguous 1024-block chunk =
    // 8 whole batches; strip-then-row order inside (R9-proven).
    const int lin = blockIdx.x + (blockIdx.y << 2) + (blockIdx.z << 7);
    const int swz = ((lin & 7) << 10) + (lin >> 3);
    const int sx0 = (swz & 3) << 7;            // strip origin x (0..384)
    const int y16 = (swz >> 2) & 31;           // tile-row
    const int b   = swz >> 7;                  // batch

    const int tx  = threadIdx.x;               // 0..15
    const int ty  = threadIdx.y;               // 0..15
    const int y   = (y16 << 4) + ty;

    // ---- Per-batch setup (amortized over 8 tiles).
    const float angle = (m_rot[b] > 0) ? (u_angle[b] * 2.0f - 1.0f) * 3.14159265358979323846f : 0.0f;
    const float sc    = (m_scale[b] > 0) ? (u_scale[b] * 2.0f - 1.0f) * SCALE_STD + 1.0f : 1.0f;
    const float tr    = (m_trans[b] > 0) ? (u_trans[b] * 2.0f - 1.0f) * TRANSLATE_STD : 0.0f;
    const float bb    = (m_bright[b] > 0) ? u_bright[b] * 0.2f : 0.0f;
    const float cc    = (m_contrast[b] > 0) ? u_contrast[b] + 0.5f : 1.0f;
    const float ss    = (m_sat[b] > 0) ? u_sat[b] * 2.0f : 1.0f;
    const bool  flip  = m_flip[b] > 0;
    const bool  docut = m_cut[b] > 0;
    const int   cy0   = y0p[b];
    const int   cx0   = x0p[b];

    float saf, caf;
    __sincosf(angle, &saf, &caf);

    // Incremental affine basis (validated R6..R11).
    const float kk = sc * (512.0f / 511.0f);
    const float dxdx = caf * kk, dxdy = -saf * kk;
    const float dydx = saf * kk, dydy = caf * kk;
    const float xx_org = 256.0f * (sc * (saf - caf) + tr + 1.0f) - 0.5f;
    const float yy_org = 256.0f * (sc * (-saf - caf) + tr + 1.0f) - 0.5f;

    const float step_x = 16.0f * dxdx;
    const float step_y = 16.0f * dydx;

    float xxt = xx_org + (float)(sx0 + tx) * dxdx + (float)y * dxdy;
    float yyt = yy_org + (float)(sx0 + tx) * dydx + (float)y * dydy;

    const float* __restrict__ imgb = images + (size_t)b * (Cn * PLANE);
    float* __restrict__ outb       = out    + (size_t)b * (Cn * PLANE);
    const float* __restrict__ noib = noise  + (size_t)b * (Cn * PLANE);

    const bool ycut = docut && (y >= cy0) && (y < cy0 + CUT_H);
    uint32_t opix = (uint32_t)y * 512u + (uint32_t)(sx0 + tx);

    if (saf != 0.0f) {
        // ================= ROTATED PATH: R11 staged pipeline =================
        const float fty = (float)(y16 << 4);
        float bx = xx_org + (float)sx0 * dxdx + fty * dxdy;   // rolling corner
        float by = yy_org + (float)sx0 * dydx + fty * dydy;
        const float sxx = 15.0f * dxdx, sxy = 15.0f * dxdy;
        const float syx = 15.0f * dydx, syy = 15.0f * dydy;
        const float min_dx = fminf(sxx, 0.0f) + fminf(sxy, 0.0f);
        const float min_dy = fminf(syx, 0.0f) + fminf(syy, 0.0f);
        const float max_dy = fmaxf(syx, 0.0f) + fmaxf(syy, 0.0f);

        // Staging lane geometry: 32 virtual rows x 8 quad-columns.
        const int tid = ty * 16 + tx;
        const int sr  = tid >> 3;            // staged virtual row 0..31
        const int sq  = (tid & 7) << 2;      // virtual col offset 0,4,..,28

        int cx_lo, cy_lo, cfh;
        int nx_lo, ny_lo, nfh;
        auto mkbox = [&](float bxv, float byv, int& x_lo, int& y_lo, int& fh) {
            x_lo = (int)floorf(bxv + min_dx) - 1;
            y_lo = (int)floorf(byv + min_dy) - 1;
            fh   = min(((int)floorf(byv + max_dy) + 2) - y_lo + 1, FH_MAX);
        };

        f4v A{}, Bq{}, Cq{};
        bool rev = false;
        auto loadR = [&](int x_lo, int y_lo) {
            const uint32_t ro = (uint32_t)refl(y_lo + sr) * 512u;
            const int c0 = x_lo + sq;
            int S0 = refl(c0);     if (flip) S0 = 511 - S0;
            int S3 = refl(c0 + 3); if (flip) S3 = 511 - S3;
            const int d = S3 - S0;
            if (d == 3) {                     // contiguous ascending
                rev = false;
                __builtin_memcpy(&A,  imgb + ro + S0, 16);
                __builtin_memcpy(&Bq, imgb + ro + S0 + PLANE, 16);
                __builtin_memcpy(&Cq, imgb + ro + S0 + 2 * PLANE, 16);
            } else if (d == -3) {             // contiguous descending
                rev = true;
                __builtin_memcpy(&A,  imgb + ro + S3, 16);
                __builtin_memcpy(&Bq, imgb + ro + S3 + PLANE, 16);
                __builtin_memcpy(&Cq, imgb + ro + S3 + 2 * PLANE, 16);
            } else {                          // fold inside quad (rare)
                rev = false;
                int S1 = refl(c0 + 1); if (flip) S1 = 511 - S1;
                int S2 = refl(c0 + 2); if (flip) S2 = 511 - S2;
                A  = f4v{imgb[ro + S0], imgb[ro + S1], imgb[ro + S2], imgb[ro + S3]};
                const float* p1 = imgb + PLANE;
                Bq = f4v{p1[ro + S0], p1[ro + S1], p1[ro + S2], p1[ro + S3]};
                const float* p2 = imgb + 2 * PLANE;
                Cq = f4v{p2[ro + S0], p2[ro + S1], p2[ro + S2], p2[ro + S3]};
            }
        };
        auto writeR = [&]() {
            f4v a = A, b2 = Bq, c2 = Cq;
            if (rev) {
                a  = f4v{A.w,  A.z,  A.y,  A.x};
                b2 = f4v{Bq.w, Bq.z, Bq.y, Bq.x};
                c2 = f4v{Cq.w, Cq.z, Cq.y, Cq.x};
            }
            float* d = &lds[sr * FSTRIDE + sq];
            *(f4v*)(d)              = a;
            *(f4v*)(d + CH_LDS)     = b2;
            *(f4v*)(d + 2 * CH_LDS) = c2;
        };

        // Prologue: tile0 staged; tile1 loads in flight.
        mkbox(bx, by, cx_lo, cy_lo, cfh);
        if (sr < cfh) { loadR(cx_lo, cy_lo); writeR(); }
        bx += step_x; by += step_y;
        mkbox(bx, by, nx_lo, ny_lo, nfh);
        if (sr < nfh) loadR(nx_lo, ny_lo);
        pipe_barrier();                        // publish tile0

        #pragma unroll 1
        for (int t = 0; t < NT; ++t) {
            const float fx = xxt - (float)cx_lo;
            const float fy = yyt - (float)cy_lo;
            const int xi = (int)fx;
            const int yi = (int)fy;
            const float wx = fx - (float)xi;
            const float wy = fy - (float)yi;
            const float* p = &lds[yi * FSTRIDE + xi];

            float vals[Cn];
            #pragma unroll
            for (int c = 0; c < Cn; ++c) {
                const float v00 = p[0], v01 = p[1];
                const float v10 = p[FSTRIDE], v11 = p[FSTRIDE + 1];
                p += CH_LDS;
                const float top = v00 + wx * (v01 - v00);
                const float bot = v10 + wx * (v11 - v10);
                float v = top + wy * (bot - top);
                v = __builtin_amdgcn_fmed3f(v + bb, -1.0f, 1.0f);
                v = __builtin_amdgcn_fmed3f(v * cc, -1.0f, 1.0f);
                vals[c] = v;
            }

            const float gray = (vals[0] + vals[1] + vals[2]) * (1.0f / 3.0f);
            const int xpix = sx0 + (t << 4) + tx;
            const bool cut = ycut && (xpix >= cx0) && (xpix < cx0 + CUT_W);
            #pragma unroll
            for (int c = 0; c < Cn; ++c) {
                float v = gray + ss * (vals[c] - gray);
                v = __builtin_amdgcn_fmed3f(v, -1.0f, 1.0f);
                if (cut) v = noib[opix + c * PLANE];
                outb[opix + c * PLANE] = v;
            }
            opix += 16;
            xxt += step_x; yyt += step_y;

            if (t == NT - 1) break;

            pipe_barrier();                    // all reads of tile t done
            cx_lo = nx_lo; cy_lo = ny_lo; cfh = nfh;
            if (sr < cfh) writeR();
            bx += step_x; by += step_y;
            if (t + 2 < NT) {
                mkbox(bx, by, nx_lo, ny_lo, nfh);
                if (sr < nfh) loadR(nx_lo, ny_lo);
            } else {
                nfh = 0;
            }
            pipe_barrier();                    // publish tile t+1
        }
    } else {
        // ===== AXIS PATH: direct gather (R9 fallback, verbatim math). =====
        // angle == 0 exactly: lanes' taps are consecutive (x spacing = dxdx
        // in [0.8,1.2]) and rows per-lane-row uniform -> ~5-6 cache lines
        // per load instr. No LDS, no barriers.
        #pragma unroll 1
        for (int t = 0; t < NT; ++t) {
            const float rxx = reflect_coord(xxt, (float)Wn);
            const float ryy = reflect_coord(yyt, (float)Hn);
            const float x0f = floorf(rxx);
            const float y0f = floorf(ryy);
            const float wx = rxx - x0f;
            const float wy = ryy - y0f;
            int x0i = (int)fminf(fmaxf(x0f, 0.0f), 511.0f);
            int x1i = (int)fminf(x0f + 1.0f, 511.0f);
            const int y0i = (int)fminf(fmaxf(y0f, 0.0f), 511.0f);
            const int y1i = (int)fminf(y0f + 1.0f, 511.0f);
            if (flip) { x0i = 511 - x0i; x1i = 511 - x1i; }
            const int xbase = min(min(x0i, x1i), 510);
            const bool s0 = (x0i != xbase);
            const bool s1 = (x1i != xbase);
            const uint32_t r0 = (uint32_t)(y0i * 512 + xbase);
            const uint32_t r1 = (uint32_t)(y1i * 512 + xbase);

            float vals[Cn];
            #pragma unroll
            for (int c = 0; c < Cn; ++c) {
                const f2v t0 = load2(imgb + r0 + c * PLANE);
                const f2v t1 = load2(imgb + r1 + c * PLANE);
                const float v00 = s0 ? t0.y : t0.x;
                const float v01 = s1 ? t0.y : t0.x;
                const float v10 = s0 ? t1.y : t1.x;
                const float v11 = s1 ? t1.y : t1.x;
                const float top = v00 + wx * (v01 - v00);
                const float bot = v10 + wx * (v11 - v10);
                float v = top + wy * (bot - top);
                v = __builtin_amdgcn_fmed3f(v + bb, -1.0f, 1.0f);
                v = __builtin_amdgcn_fmed3f(v * cc, -1.0f, 1.0f);
                vals[c] = v;
            }

            const float gray = (vals[0] + vals[1] + vals[2]) * (1.0f / 3.0f);
            const int xpix = sx0 + (t << 4) + tx;
            const bool cut = ycut && (xpix >= cx0) && (xpix < cx0 + CUT_W);
            #pragma unroll
            for (int c = 0; c < Cn; ++c) {
                float v = gray + ss * (vals[c] - gray);
                v = __builtin_amdgcn_fmed3f(v, -1.0f, 1.0f);
                if (cut) v = noib[opix + c * PLANE];
                outb[opix + c * PLANE] = v;
            }
            opix += 16;
            xxt += step_x; yyt += step_y;
        }
    }
}

extern "C" void kernel_launch(void* const* d_in, const int* in_sizes, int n_in,
                              void* d_out, int out_size, void* d_ws, size_t ws_size,
                              hipStream_t stream) {
    const float* images     = (const float*)d_in[0];
    const float* u_angle    = (const float*)d_in[1];
    const float* u_scale    = (const float*)d_in[2];
    const float* u_trans    = (const float*)d_in[3];
    const float* u_bright   = (const float*)d_in[4];
    const float* u_contrast = (const float*)d_in[5];
    const float* u_sat      = (const float*)d_in[6];
    const float* noise      = (const float*)d_in[7];
    const int*   m_flip     = (const int*)d_in[8];
    const int*   m_rot      = (const int*)d_in[9];
    const int*   m_scale    = (const int*)d_in[10];
    const int*   m_trans    = (const int*)d_in[11];
    const int*   m_bright   = (const int*)d_in[12];
    const int*   m_contrast = (const int*)d_in[13];
    const int*   m_sat      = (const int*)d_in[14];
    const int*   m_cut      = (const int*)d_in[15];
    const int*   y0p        = (const int*)d_in[16];
    const int*   x0p        = (const int*)d_in[17];
    float* out = (float*)d_out;

    dim3 block(16, 16);
    dim3 grid(Wn / (16 * NT), Hn / 16, Bn);   // (4, 32, 64) = 8192 blocks
    augment_kernel<<<grid, block, 0, stream>>>(
        images, u_angle, u_scale, u_trans, u_bright, u_contrast, u_sat, noise,
        m_flip, m_rot, m_scale, m_trans, m_bright, m_contrast, m_sat, m_cut,
        y0p, x0p, out);
}